// Round 7
// baseline (616.457 us; speedup 1.0000x reference)
//
#include <hip/hip_runtime.h>
#include <hip/hip_bf16.h>

// Problem constants
#define Mdim 2048
#define Ndim 8192
#define Kdim 8192
#define NT (Kdim / 64)   // 128 K-tiles of BK=64

typedef __bf16 bf16x8 __attribute__((ext_vector_type(8)));
typedef float f32x4 __attribute__((ext_vector_type(4)));
typedef unsigned short ushort4v __attribute__((ext_vector_type(4)));

__device__ __forceinline__ unsigned short f2bf_rne(float f) {
    unsigned u = __float_as_uint(f);
    u += 0x7fffu + ((u >> 16) & 1u);
    return (unsigned short)(u >> 16);
}

// ---------------------------------------------------------------------------
// k_prep: [0,16384) x fp32->bf16 ; [16384,20480) codebook fp32->bf16.
// ---------------------------------------------------------------------------
__global__ __launch_bounds__(256) void k_prep(const float* __restrict__ x,
                                              const float* __restrict__ cb,
                                              unsigned short* __restrict__ xb,
                                              unsigned short* __restrict__ cbb) {
    const int t = threadIdx.x;
    if (blockIdx.x < 16384) {
        const size_t u = (size_t)blockIdx.x * 256 + t;       // 0..4194303
        float4 a = ((const float4*)x)[u];
        ushort4v o;
        o[0] = f2bf_rne(a.x); o[1] = f2bf_rne(a.y);
        o[2] = f2bf_rne(a.z); o[3] = f2bf_rne(a.w);
        ((ushort4v*)xb)[u] = o;
    } else {
        const size_t u = (size_t)(blockIdx.x - 16384) * 256 + t;  // 0..1048575
        float4 a = ((const float4*)cb)[u];
        ushort4v o;
        o[0] = f2bf_rne(a.x); o[1] = f2bf_rne(a.y);
        o[2] = f2bf_rne(a.z); o[3] = f2bf_rne(a.w);
        ((ushort4v*)cbb)[u] = o;
    }
}

// ---------------------------------------------------------------------------
// Fused dequant+GEMM: R6 skeleton (XCD-pinned mapping bm=bid>>5, bn=bid&31;
// counted vmcnt; 1 barrier/phase; XOR-chunk swizzle) with B decoded in-kernel.
// Readers of a bn-panel all live on XCD bn&7 -> that panel's packed (768KB)
// + cbb (128KB) working set is L2-resident -> decode operands never re-fetch
// HBM (R3/R4's failure mode, FETCH 492-555MB, is structurally removed).
// B-path per tile: 3x int4 packed + 1x int4 cbb reg-loads (issued P3, one
// tile ahead), perm-decode 2 groups in P1 + 2 in P2, swizzled ds_write_b128
// into LB[buf^1]. bLo/bHi single reg sets read phase-ahead (P3-end / P0-end).
// vmcnt ledger (G=gld16 A-stage pair, R=4 B reg-loads; per tile issues:
// P0: G[A(T+1)hi], P3: G[A(T+2)lo] + R[B(T+2)]):
//   P1: VMCNT(8)  forces A(T,hi)   [newer: G+R @P3(T-1), G @P0(T) = 8]
//   P3: VMCNT(12) forces A(T+1,lo) [newer: R@P3(T-1), G@P0(T), G+R@P3(T)]
//       tail: VMCNT(6) @T=NT-2, none @NT-1
// Decode's reg use adds compiler vmcnt waits that are tighter subsets - safe.
// LGKM0 before the P1/P2 barriers publishes decode's ds_writes.
// WAR: every LDS slot overwrite is >=1 barrier after its reads completed
// (reads complete before their consuming MFMA, which precedes that barrier).
// ---------------------------------------------------------------------------
__device__ __forceinline__ void gld16(const unsigned short* g, unsigned short* l) {
    __builtin_amdgcn_global_load_lds(
        (const __attribute__((address_space(1))) unsigned int*)g,
        (__attribute__((address_space(3))) unsigned int*)l, 16, 0, 0);
}

#define BAR()    asm volatile("s_barrier" ::: "memory")
#define FENCE()  asm volatile("" ::: "memory")
#define SBAR0()  __builtin_amdgcn_sched_barrier(0)
#define LGKM0()  asm volatile("s_waitcnt lgkmcnt(0)" ::: "memory")
#define VMCNT(n) asm volatile("s_waitcnt vmcnt(" #n ")" ::: "memory")

// Decode one 8-elem group (24 payload bits) vs bf16-packed codebook pairs
// (P0=e1:e0 .. P3=e7:e6). Proven bit-exact in R3/R4.
__device__ __forceinline__ uint4 dec_group(unsigned b, unsigned P0, unsigned P1,
                                           unsigned P2, unsigned P3) {
    uint4 o;
#pragma unroll
    for (int k = 0; k < 4; ++k) {
        unsigned ia = (b >> (6 * k)) & 3u;
        unsigned ib = (b >> (6 * k + 3)) & 3u;
        unsigned sel = ia * 0x0202u + 0x01000100u + ((ib * 0x0202u) << 16);
        unsigned lo = __builtin_amdgcn_perm(P1, P0, sel);
        unsigned hi = __builtin_amdgcn_perm(P3, P2, sel);
        unsigned mA = (unsigned)((int)(b << (29 - 6 * k)) >> 31);
        unsigned mB = (unsigned)((int)(b << (26 - 6 * k)) >> 31);
        unsigned m = (mA & 0xFFFFu) | (mB & 0xFFFF0000u);
        (&o.x)[k] = (hi & m) | (lo & ~m);
    }
    return o;
}

__global__ __launch_bounds__(512, 2) void k_gemm(const unsigned short* __restrict__ A,
                                                 const int* __restrict__ packed,
                                                 const unsigned short* __restrict__ cbb,
                                                 float* __restrict__ C) {
    __shared__ unsigned short LA[4 * 8192];   // [buf][half][128*64] = 64 KB
    __shared__ unsigned short LB[4 * 8192];   // 64 KB (decoded W)

    const int tid  = threadIdx.x;
    const int lane = tid & 63;
    const int wave = tid >> 6;               // 0..7
    const int qm = wave >> 2;                // 0..1
    const int qn = wave & 3;                 // 0..3

    const int bid = blockIdx.x;
    const int bm = (bid >> 5) * 256;         // 8 A panels
    const int bn = (bid & 31) * 256;         // W panel; XCD = bid&7 = bn&7

    // ---- A staging (global_load_lds, pre-swizzled source) ----
    const int chunk0 = tid, chunk1 = tid + 512;
    const int srow0 = chunk0 >> 3, srow1 = chunk1 >> 3;
    const int scol0 = ((chunk0 & 7) ^ (srow0 & 7)) * 8;
    const int scol1 = ((chunk1 & 7) ^ (srow1 & 7)) * 8;
    const unsigned short* Ag0 = A + (size_t)(bm + srow0) * Kdim + scol0;
    const unsigned short* Ag1 = A + (size_t)(bm + srow1) * Kdim + scol1;

#define STAGE_A(T, H, BUF) do {                                                   \
    unsigned short* _d = LA + ((BUF) * 2 + (H)) * 8192;                           \
    gld16(Ag0 + (size_t)(H) * 128 * Kdim + (size_t)(T) * 64, _d + (size_t)tid * 8);        \
    gld16(Ag1 + (size_t)(H) * 128 * Kdim + (size_t)(T) * 64, _d + (size_t)(tid + 512) * 8);\
    FENCE();                                                                      \
} while (0)

    // ---- B decode addressing: 2 threads/row, 4 groups (32 elems) each ----
    const int drow  = tid >> 1;              // 0..255 (panel row)
    const int dp    = tid & 1;               // elems [32dp, 32dp+32)
    const int dhalf = drow >> 7;
    const int drr   = drow & 127;
    const int drlo  = drr & 7;
    const int dp4   = dp * 4;
    const int* Pg   = packed + (size_t)(bn + drow) * 3072 + dp * 12;
    const unsigned short* Cgb = cbb + (size_t)(bn + drow) * 512;  // 64 blk x 8

    int4 bq0, bq1, bq2;   // packed payload, in flight one tile ahead
    int4 cq;              // bf16-packed codebook block (8 entries)

#define B_ISSUE(TT) do {                                                          \
    const int4* _pp = (const int4*)(Pg + (size_t)(TT) * 24);                      \
    bq0 = _pp[0]; bq1 = _pp[1]; bq2 = _pp[2];                                     \
    cq = *(const int4*)(Cgb + (size_t)((TT) >> 1) * 8);                           \
} while (0)

#define DECG(G, W0, W1, W2, BUFW) do {                                            \
    unsigned _b = (unsigned)((W0) & 255) | (((unsigned)((W1) & 255)) << 8) |      \
                  (((unsigned)((W2) & 255)) << 16);                               \
    uint4 _o = dec_group(_b, (unsigned)cq.x, (unsigned)cq.y,                      \
                         (unsigned)cq.z, (unsigned)cq.w);                         \
    *(uint4*)&LB[((BUFW) * 2 + dhalf) * 8192 + drr * 64 +                         \
                 (((dp4 + (G)) ^ drlo) << 3)] = _o;                               \
} while (0)

#define DECODE_H1(BUFW) do {                                                      \
    DECG(0, bq0.x, bq0.y, bq0.z, BUFW);                                           \
    DECG(1, bq0.w, bq1.x, bq1.y, BUFW);                                           \
} while (0)
#define DECODE_H2(BUFW) do {                                                      \
    DECG(2, bq1.z, bq1.w, bq2.x, BUFW);                                           \
    DECG(3, bq2.y, bq2.z, bq2.w, BUFW);                                           \
} while (0)

    // ---- fragment read addressing (swizzled) ----
    const int r15 = lane & 15;
    const int q   = lane >> 4;
    const int rlo = r15 & 7;
    const int aro = qm * 64 + r15;
    const int bro = qn * 32 + r15;
    const int ch0 = ((0 + q) ^ rlo) * 8;
    const int ch1 = ((4 + q) ^ rlo) * 8;

    f32x4 acc[4][4][2];
    const f32x4 zero = {0.f, 0.f, 0.f, 0.f};
#pragma unroll
    for (int p = 0; p < 4; ++p)
#pragma unroll
        for (int i = 0; i < 4; ++i)
#pragma unroll
            for (int j = 0; j < 2; ++j) acc[p][i][j] = zero;

    bf16x8 aF[4][2];     // A: lo (P0,P1) then hi (P2,P3), reg-reused
    bf16x8 bLo[2][2];    // B lo half (P0,P3), single set
    bf16x8 bHi[2][2];    // B hi half (P1,P2), single set

#define LOAD_AF(BUF, H) do {                                                      \
    const unsigned short* _s = LA + ((BUF) * 2 + (H)) * 8192;                     \
    _Pragma("unroll") for (int i = 0; i < 4; ++i) {                               \
        int _r = (aro + i * 16) * 64;                                             \
        aF[i][0] = *(const bf16x8*)&_s[_r + ch0];                                 \
        aF[i][1] = *(const bf16x8*)&_s[_r + ch1];                                 \
    }                                                                             \
} while (0)
#define LOAD_BF(SET, BUF, H) do {                                                 \
    const unsigned short* _s = LB + ((BUF) * 2 + (H)) * 8192;                     \
    _Pragma("unroll") for (int j = 0; j < 2; ++j) {                               \
        int _r = (bro + j * 16) * 64;                                             \
        SET[j][0] = *(const bf16x8*)&_s[_r + ch0];                                \
        SET[j][1] = *(const bf16x8*)&_s[_r + ch1];                                \
    }                                                                             \
} while (0)

#define MFMA_PH(P, SET) do {                                                      \
    __builtin_amdgcn_s_setprio(1);                                                \
    _Pragma("unroll") for (int i = 0; i < 4; ++i)                                 \
    _Pragma("unroll") for (int j = 0; j < 2; ++j) {                               \
        acc[P][i][j] = __builtin_amdgcn_mfma_f32_16x16x32_bf16(                   \
            aF[i][0], SET[j][0], acc[P][i][j], 0, 0, 0);                          \
        acc[P][i][j] = __builtin_amdgcn_mfma_f32_16x16x32_bf16(                   \
            aF[i][1], SET[j][1], acc[P][i][j], 0, 0, 0);                          \
    }                                                                             \
    __builtin_amdgcn_s_setprio(0);                                                \
} while (0)

// Phases: P0=(Alo,Blo) P1=(Alo,Bhi) P2=(Ahi,Bhi) P3=(Ahi,Blo).
#define KSTEP(T, BUF) do {                                                        \
    /* P0 */                                                                      \
    if ((T) + 1 < NT) STAGE_A((T) + 1, 1, (BUF) ^ 1);                             \
    MFMA_PH(0, bLo);                                                              \
    SBAR0();                                                                      \
    LOAD_BF(bHi, BUF, 1);                 /* Bhi(T) for P1,P2 */                  \
    BAR();                                                                        \
    /* P1 */                                                                      \
    MFMA_PH(1, bHi);                                                              \
    if ((T) + 1 < NT) DECODE_H1((BUF) ^ 1);   /* B(T+1) groups 0,1 */             \
    SBAR0();                                                                      \
    if ((T) + 1 < NT) { VMCNT(8); } else { VMCNT(0); }                            \
    LOAD_AF(BUF, 1);                      /* Ahi(T) for P2,P3 */                  \
    LGKM0(); BAR();                                                               \
    /* P2 */                                                                      \
    MFMA_PH(2, bHi);                                                              \
    if ((T) + 1 < NT) DECODE_H2((BUF) ^ 1);   /* B(T+1) groups 2,3 */             \
    LGKM0(); BAR();                                                               \
    /* P3 */                                                                      \
    MFMA_PH(3, bLo);                                                              \
    if ((T) + 2 < NT) { STAGE_A((T) + 2, 0, BUF); B_ISSUE((T) + 2); }             \
    SBAR0();                                                                      \
    if ((T) + 2 < NT)      { VMCNT(12); }                                         \
    else if ((T) + 1 < NT) { VMCNT(6); }                                          \
    if ((T) + 1 < NT) { LOAD_AF((BUF) ^ 1, 0); LOAD_BF(bLo, (BUF) ^ 1, 0); }      \
    BAR();                                                                        \
} while (0)

    // ---- Prologue ----
    STAGE_A(0, 0, 0); STAGE_A(0, 1, 0); STAGE_A(1, 0, 1);   // 6 gld16
    {   // decode B(0) -> LB[0] (plain loads; compiler inserts waits)
        const int4* pp = (const int4*)Pg;
        int4 w0 = pp[0], w1 = pp[1], w2 = pp[2];
        cq = *(const int4*)(Cgb);                 // block 0
        bq0 = w0; bq1 = w1; bq2 = w2;
        DECODE_H1(0); DECODE_H2(0);
    }
    B_ISSUE(1);                  // B(1) regs, left in flight
    VMCNT(4);                    // force the 6 gld16; keep B(1)'s 4 in flight
    LGKM0(); BAR();
    LOAD_AF(0, 0);               // Alo(0)
    LOAD_BF(bLo, 0, 0);          // Blo(0)

    for (int t2 = 0; t2 < NT; t2 += 2) {
        KSTEP(t2, 0);
        KSTEP(t2 + 1, 1);
    }

    // ---- Epilogue: C/D layout col = lane&15, row = (lane>>4)*4 + r ----
    constexpr int RHs[4] = {0, 0, 1, 1};
    constexpr int CHs[4] = {0, 1, 1, 0};
#pragma unroll
    for (int p = 0; p < 4; ++p) {
#pragma unroll
        for (int i = 0; i < 4; ++i) {
#pragma unroll
            for (int j = 0; j < 2; ++j) {
                int row = bm + RHs[p] * 128 + qm * 64 + i * 16 + q * 4;
                int col = bn + CHs[p] * 128 + qn * 32 + j * 16 + r15;
                float* outp = C + (size_t)row * Ndim + col;
#pragma unroll
                for (int r = 0; r < 4; ++r)
                    outp[(size_t)r * Ndim] = acc[p][i][j][r];
            }
        }
    }

#undef STAGE_A
#undef B_ISSUE
#undef DECG
#undef DECODE_H1
#undef DECODE_H2
#undef LOAD_AF
#undef LOAD_BF
#undef MFMA_PH
#undef KSTEP
}

// ---------------------------------------------------------------------------
extern "C" void kernel_launch(void* const* d_in, const int* in_sizes, int n_in,
                              void* d_out, int out_size, void* d_ws, size_t ws_size,
                              hipStream_t stream) {
    const float* x      = (const float*)d_in[0];   // 2048 x 8192 fp32
    const int*   packed = (const int*)d_in[1];     // 25165824 int32 (one byte each)
    const float* cb     = (const float*)d_in[2];   // 524288 x 8 fp32
    float* out = (float*)d_out;                    // 2048 x 8192 fp32

    unsigned short* Xb  = (unsigned short*)d_ws;                           // 32 MB bf16 x
    unsigned short* Cbb = (unsigned short*)d_ws + (size_t)Mdim * Kdim;     // 8 MB bf16 cb

    // 1) prep: x fp32->bf16 + codebook fp32->bf16
    k_prep<<<20480, 256, 0, stream>>>(x, cb, Xb, Cbb);
    // 2) fused dequant+GEMM: 256 blocks (1/CU), 512 thr, 128 KB LDS
    k_gemm<<<dim3(256), 512, 0, stream>>>(Xb, packed, Cbb, out);
}